// Round 1
// baseline (328.428 us; speedup 1.0000x reference)
//
#include <hip/hip_runtime.h>

#define N_COLS 3072
#define N_ROWS 3072
#define N_CH   3
#define NPIX   ((size_t)N_COLS * N_ROWS)
#define NTOT   (N_CH * NPIX)
#define RED_BLOCKS  1024
#define RED_THREADS 256

// Kernel 1: copy inp -> out (float4 vectorized) and reduce global max into
// per-block partials in d_ws (each slot written unconditionally -> replay-safe).
__global__ __launch_bounds__(RED_THREADS)
void copy_max_kernel(const float* __restrict__ in, float* __restrict__ out,
                     float* __restrict__ partial) {
    const float4* in4  = (const float4*)in;
    float4*       out4 = (float4*)out;
    const int n4 = (int)(NTOT / 4);   // 7,077,888 — fits int
    float m = -INFINITY;
    for (int i = blockIdx.x * blockDim.x + threadIdx.x; i < n4;
         i += gridDim.x * blockDim.x) {
        float4 v = in4[i];
        out4[i] = v;
        m = fmaxf(m, fmaxf(fmaxf(v.x, v.y), fmaxf(v.z, v.w)));
    }
    // wave (64-lane) reduce
    #pragma unroll
    for (int off = 32; off > 0; off >>= 1)
        m = fmaxf(m, __shfl_down(m, off, 64));
    __shared__ float smax[RED_THREADS / 64];
    const int lane = threadIdx.x & 63;
    const int wid  = threadIdx.x >> 6;
    if (lane == 0) smax[wid] = m;
    __syncthreads();
    if (threadIdx.x == 0) {
        float r = smax[0];
        #pragma unroll
        for (int w = 1; w < RED_THREADS / 64; ++w) r = fmaxf(r, smax[w]);
        partial[blockIdx.x] = r;
    }
}

// Kernel 2: one wave per crack. All 64 lanes walk the Bresenham line
// redundantly (wave-uniform); lane l < 27 owns stamp offset
// (c = l/9, dw = (l%9)/3, dl = l%3) and stores val each step.
__global__ __launch_bounds__(64)
void paint_kernel(const int* __restrict__ x_start, const int* __restrict__ x_end,
                  const int* __restrict__ y_start, const int* __restrict__ y_end,
                  const int* __restrict__ length,  const int* __restrict__ width,
                  float* __restrict__ out, const float* __restrict__ partial) {
    const int lane = threadIdx.x;

    // Redundant reduction of the 1024 block-partials to the global max.
    float m = -INFINITY;
    for (int i = lane; i < RED_BLOCKS; i += 64) m = fmaxf(m, partial[i]);
    #pragma unroll
    for (int off = 32; off > 0; off >>= 1)
        m = fmaxf(m, __shfl_down(m, off, 64));
    const float val = __shfl(m, 0, 64);

    const int b  = blockIdx.x;
    const int x0 = x_start[b], x1 = x_end[b];
    const int y0 = y_start[b], y1 = y_end[b];
    const int W  = width[b],   L  = length[b];

    // Reference: done0 = (start == end) -> nothing painted at all.
    if (x0 == x1 && y0 == y1) return;

    const int c  = lane / 9;
    const int rem = lane % 9;
    const int dw = rem / 3;
    const int dl = rem % 3;
    const bool active = (lane < 27) && (dw < W) && (dl < L);
    const size_t cbase = (size_t)(active ? c : 0) * NPIX;

    const int dx = abs(x1 - x0), dy = abs(y1 - y0);
    const int sx = (x0 < x1) ? 1 : -1;
    const int sy = (y0 < y1) ? 1 : -1;
    int err = dx - dy;
    int x = x0, y = y0;

    // Paint current pixel, then step; endpoint itself is NOT painted
    // (reference sets done after the move, so the emitted (x,y) at the
    // iteration where we've already arrived has active=false).
    for (int step = 0; step < N_COLS + N_ROWS; ++step) {
        const int yy = y + dw;
        const int xx = x + dl;
        if (active && yy < N_COLS && xx < N_ROWS)
            out[cbase + (size_t)yy * N_ROWS + xx] = val;
        const int e2 = 2 * err;
        const bool cx = (e2 > -dy);
        const bool cy = (e2 <  dx);
        if (cx) { err -= dy; x += sx; }
        if (cy) { err += dx; y += sy; }
        if (x == x1 && y == y1) break;
    }
}

extern "C" void kernel_launch(void* const* d_in, const int* in_sizes, int n_in,
                              void* d_out, int out_size, void* d_ws, size_t ws_size,
                              hipStream_t stream) {
    const float* inp     = (const float*)d_in[0];
    const int*   x_start = (const int*)d_in[1];
    const int*   x_end   = (const int*)d_in[2];
    const int*   y_start = (const int*)d_in[3];
    const int*   y_end   = (const int*)d_in[4];
    const int*   length  = (const int*)d_in[5];
    const int*   width   = (const int*)d_in[6];
    float*       out     = (float*)d_out;
    float*       partial = (float*)d_ws;   // RED_BLOCKS floats

    copy_max_kernel<<<RED_BLOCKS, RED_THREADS, 0, stream>>>(inp, out, partial);
    paint_kernel<<<64, 64, 0, stream>>>(x_start, x_end, y_start, y_end,
                                        length, width, out, partial);
}

// Round 2
// 52.906 us; speedup vs baseline: 6.2077x; 6.2077x over previous
//
#include <hip/hip_runtime.h>

#define N_COLS 3072
#define N_ROWS 3072
#define N_CH   3
#define NPIX   ((size_t)N_COLS * N_ROWS)
#define NTOT   (N_CH * NPIX)
#define RED_BLOCKS  1024
#define RED_THREADS 256
#define PAINT_THREADS 256
#define PAINT_CHUNKS  12   // 12*256 = 3072 >= max nsteps (3071)

// Kernel 1: copy inp -> out (float4) + global-max partials into d_ws.
// Every partial slot is written unconditionally each call -> replay-safe.
__global__ __launch_bounds__(RED_THREADS)
void copy_max_kernel(const float* __restrict__ in, float* __restrict__ out,
                     float* __restrict__ partial) {
    const float4* in4  = (const float4*)in;
    float4*       out4 = (float4*)out;
    const int n4 = (int)(NTOT / 4);
    float m = -INFINITY;
    for (int i = blockIdx.x * blockDim.x + threadIdx.x; i < n4;
         i += gridDim.x * blockDim.x) {
        float4 v = in4[i];
        out4[i] = v;
        m = fmaxf(m, fmaxf(fmaxf(v.x, v.y), fmaxf(v.z, v.w)));
    }
    #pragma unroll
    for (int off = 32; off > 0; off >>= 1)
        m = fmaxf(m, __shfl_down(m, off, 64));
    __shared__ float smax[RED_THREADS / 64];
    const int lane = threadIdx.x & 63;
    const int wid  = threadIdx.x >> 6;
    if (lane == 0) smax[wid] = m;
    __syncthreads();
    if (threadIdx.x == 0) {
        float r = smax[0];
        #pragma unroll
        for (int w = 1; w < RED_THREADS / 64; ++w) r = fmaxf(r, smax[w]);
        partial[blockIdx.x] = r;
    }
}

// Kernel 2: closed-form Bresenham rasterization, one thread per line step.
//
// For this both-axis variant with dx >= dy, cx fires every step (invariant
// 2*err > -dy), so step k paints (x0 + sx*k, y0 + sy*c_k) with
//   c_k = max(0, ceil((2k*dy - dx) / (2dx)))
// and nsteps = dx (endpoint at k = nsteps is NOT painted, matching the
// reference's done-after-move semantics). Mirrored for dy > dx.
// Verified against the reference recurrence on (3,2),(4,1),(1,4),(5,3),
// (3,3),(2,1),(1,2),(n,0).
__global__ __launch_bounds__(PAINT_THREADS)
void paint_kernel(const int* __restrict__ x_start, const int* __restrict__ x_end,
                  const int* __restrict__ y_start, const int* __restrict__ y_end,
                  const int* __restrict__ length,  const int* __restrict__ width,
                  float* __restrict__ out, const float* __restrict__ partial) {
    const int b  = blockIdx.y;
    const int x0 = x_start[b], x1 = x_end[b];
    const int y0 = y_start[b], y1 = y_end[b];

    if (x0 == x1 && y0 == y1) return;          // done0: paints nothing

    const int dx = abs(x1 - x0), dy = abs(y1 - y0);
    const int nsteps = max(dx, dy);
    if ((int)(blockIdx.x * PAINT_THREADS) >= nsteps) return;  // block-uniform

    // Wave-redundant reduction of the 1024 partials (L2-resident, ~16 loads/lane).
    const int lane = threadIdx.x & 63;
    float m = -INFINITY;
    for (int i = lane; i < RED_BLOCKS; i += 64) m = fmaxf(m, partial[i]);
    #pragma unroll
    for (int off = 32; off > 0; off >>= 1)
        m = fmaxf(m, __shfl_down(m, off, 64));
    const float val = __shfl(m, 0, 64);

    const int k = blockIdx.x * PAINT_THREADS + threadIdx.x;
    if (k >= nsteps) return;

    const int sx = (x0 < x1) ? 1 : -1;
    const int sy = (y0 < y1) ? 1 : -1;
    int X, Y;
    if (dx >= dy) {
        X = k;
        const int num = 2 * k * dy - dx;
        Y = (num <= 0) ? 0 : (num + 2 * dx - 1) / (2 * dx);
    } else {
        Y = k;
        const int num = 2 * k * dx - dy;
        X = (num <= 0) ? 0 : (num + 2 * dy - 1) / (2 * dy);
    }
    const int px = x0 + sx * X;
    const int py = y0 + sy * Y;

    const int W = width[b], L = length[b];
    for (int dw = 0; dw < W; ++dw) {
        const int yy = py + dw;
        if (yy >= N_COLS) continue;
        for (int dl = 0; dl < L; ++dl) {
            const int xx = px + dl;
            if (xx >= N_ROWS) continue;
            const size_t p = (size_t)yy * N_ROWS + xx;
            out[p]            = val;
            out[NPIX + p]     = val;
            out[2 * NPIX + p] = val;
        }
    }
}

extern "C" void kernel_launch(void* const* d_in, const int* in_sizes, int n_in,
                              void* d_out, int out_size, void* d_ws, size_t ws_size,
                              hipStream_t stream) {
    const float* inp     = (const float*)d_in[0];
    const int*   x_start = (const int*)d_in[1];
    const int*   x_end   = (const int*)d_in[2];
    const int*   y_start = (const int*)d_in[3];
    const int*   y_end   = (const int*)d_in[4];
    const int*   length  = (const int*)d_in[5];
    const int*   width   = (const int*)d_in[6];
    float*       out     = (float*)d_out;
    float*       partial = (float*)d_ws;   // RED_BLOCKS floats

    copy_max_kernel<<<RED_BLOCKS, RED_THREADS, 0, stream>>>(inp, out, partial);
    dim3 pgrid(PAINT_CHUNKS, 64);
    paint_kernel<<<pgrid, PAINT_THREADS, 0, stream>>>(
        x_start, x_end, y_start, y_end, length, width, out, partial);
}